// Round 7
// baseline (533.576 us; speedup 1.0000x reference)
//
#include <hip/hip_runtime.h>
#include <hip/hip_cooperative_groups.h>
#include <stdint.h>
#include <math.h>

namespace cg = cooperative_groups;

#define BN_EPS 1e-3f

__device__ __forceinline__ uint32_t rfl_u32(uint32_t v) {
    return __builtin_amdgcn_readfirstlane(v);
}

// bit-pack weight signs: bit=1 <=> w<0; layout [(tap*CINW+wi)][COUT]
template <int CIN, int COUT>
__device__ inline void packw_item(const float* __restrict__ w, uint32_t* __restrict__ wp, int idx) {
    const int CINW = CIN / 32;
    int co = idx % COUT;
    int t2 = idx / COUT;
    int wi = t2 % CINW;
    int tap = t2 / CINW;
    uint32_t word = 0;
#pragma unroll
    for (int bb = 0; bb < 32; bb++) {
        float val = w[((tap * CIN) + wi * 32 + bb) * COUT + co];
        word |= (uint32_t)(val < 0.f) << bb;
    }
    wp[idx] = word;
}

// sign(bn(best)) < 0  <=>  best < m - b*sqrt(v+eps)   (rsqrt > 0 always)
__device__ inline float mk_thr(const float* m, const float* v, const float* b, int c) {
    return (float)((double)m[c] - (double)b[c] * sqrt((double)v[c] + (double)BN_EPS));
}

// ============================================================
// Fused cooperative kernel: all 5 stages, grid.sync between.
// ============================================================
__global__ __launch_bounds__(256, 4) void fused(
    const float* __restrict__ x,  const float* __restrict__ w1,
    const float* __restrict__ w2, const float* __restrict__ w3, const float* __restrict__ w4,
    const float* __restrict__ m1, const float* __restrict__ v1, const float* __restrict__ b1,
    const float* __restrict__ m2, const float* __restrict__ v2, const float* __restrict__ b2,
    const float* __restrict__ m3, const float* __restrict__ v3, const float* __restrict__ b3,
    const float* __restrict__ m4, const float* __restrict__ v4, const float* __restrict__ b4,
    uint32_t* __restrict__ w1m, float* __restrict__ thr1,
    uint32_t* __restrict__ w2p, float* __restrict__ thr2,
    uint32_t* __restrict__ w3p, float* __restrict__ thr3,
    uint32_t* __restrict__ w4p,
    uint32_t* __restrict__ y1p, uint2* __restrict__ y2p,
    uint32_t* __restrict__ y3p, float* __restrict__ out)
{
    cg::grid_group grid = cg::this_grid();
    const int lane = threadIdx.x & 63;
    const int wgid = rfl_u32((uint32_t)((blockIdx.x * 256 + threadIdx.x) >> 6));
    const int nwaves = gridDim.x * 4;

    // ================= phase 0: weight prep =================
    for (int i = blockIdx.x * 256 + threadIdx.x; i < 12347; i += gridDim.x * 256) {
        int j = i;
        if (j < 27) {
            uint32_t word = 0;
#pragma unroll
            for (int c = 0; c < 32; c++)
                word |= (uint32_t)(w1[j * 32 + c] < 0.f) << c;
            w1m[j] = word;
        } else if ((j -= 27) < 32) {
            thr1[j] = mk_thr(m1, v1, b1, j);
        } else if ((j -= 32) < 576) {
            packw_item<32, 64>(w2, w2p, j);
        } else if ((j -= 576) < 64) {
            thr2[j] = mk_thr(m2, v2, b2, j);
        } else if ((j -= 64) < 2304) {
            packw_item<64, 128>(w3, w3p, j);
        } else if ((j -= 2304) < 128) {
            thr3[j] = mk_thr(m3, v3, b3, j);
        } else if ((j -= 128) < 9216) {
            packw_item<128, 256>(w4, w4p, j);
        }
    }
    grid.sync();

    // ================= phase 1: conv1 + pool + bn + sign -> y1p =================
    {
        __shared__ float xt[18 * 56];   // 18 rows x 54 col-floats (pad 56)

        uint32_t um[27];
#pragma unroll
        for (int t = 0; t < 27; t++) um[t] = rfl_u32(w1m[t]);
        float th[32];
#pragma unroll
        for (int c = 0; c < 32; c++)
            th[c] = __uint_as_float(rfl_u32(((const uint32_t*)thr1)[c]));

        int wave = threadIdx.x >> 6;
        int r = lane >> 3, c8 = lane & 7;
        int ly = (wave >> 1) * 8 + r;            // conv row within 16x16 tile
        int lx = (wave & 1) * 8 + c8;            // conv col within tile

        for (int tile = blockIdx.x; tile < 4096; tile += gridDim.x) {
            int n = tile >> 6, ty = (tile >> 3) & 7, tx = tile & 7;
            int oy = ty * 16;                    // conv-row origin
            int oxf = tx * 48;                   // col-float origin (col*3)
            __syncthreads();
            for (int i = threadIdx.x; i < 972; i += 256) {
                int rr = i / 54, cc = i % 54;
                int gr = oy + rr, gc = oxf + cc;
                float vv = 0.f;
                if (gr < 128 && gc < 384)
                    vv = x[(size_t)(n * 128 + gr) * 384 + gc];
                xt[rr * 56 + cc] = vv;
            }
            __syncthreads();

            float win[27];
#pragma unroll
            for (int kh = 0; kh < 3; kh++)
#pragma unroll
                for (int kk = 0; kk < 9; kk++)
                    win[kh * 9 + kk] = xt[(ly + kh) * 56 + lx * 3 + kk];

            float acc[32];
#pragma unroll
            for (int ch = 0; ch < 32; ch++) acc[ch] = 0.f;
#pragma unroll
            for (int t = 0; t < 27; t++) {
                uint32_t mw = um[t];
                float xv = win[t];
#pragma unroll
                for (int ch = 0; ch < 32; ch++) {
                    float w = (mw & (1u << ch)) ? -1.f : 1.f;   // scalar select
                    acc[ch] += xv * w;
                }
            }
#pragma unroll
            for (int ch = 0; ch < 32; ch++) {
                float a = fmaxf(acc[ch], __shfl_xor(acc[ch], 1, 64));
                acc[ch] = fmaxf(a, __shfl_xor(a, 8, 64));
            }
            if (((r | c8) & 1) == 0) {
                int ph = (oy + ly) >> 1;
                int pw = (tx * 16 + lx) >> 1;
                if (ph < 63 && pw < 63) {
                    uint32_t word = 0;
#pragma unroll
                    for (int ch = 0; ch < 32; ch++)
                        word |= (uint32_t)(acc[ch] < th[ch]) << ch;
                    y1p[(n * 63 + ph) * 63 + pw] = word;
                }
            }
        }
    }
    grid.sync();

    // ================= phase 2: bconv2 -> y2p =================
    {
        uint32_t wq[9];
#pragma unroll
        for (int t = 0; t < 9; t++) wq[t] = w2p[t * 64 + lane];
        float th = thr2[lane];

        for (int item = wgid; item < 64 * 31 * 8; item += nwaves) {
            int pwg = item & 7;
            int t2 = item >> 3;
            int ph = t2 % 31;
            int n = t2 / 31;

            uint2 res[4];
            if (ph > 0 && pwg > 0) {
                int row0 = 2 * ph - 1, col0 = 8 * pwg - 1;
                uint32_t win[4][10];
#pragma unroll
                for (int rr = 0; rr < 4; rr++)
#pragma unroll
                    for (int cc = 0; cc < 10; cc++)
                        win[rr][cc] = y1p[(n * 63 + row0 + rr) * 63 + min(col0 + cc, 62)];
#pragma unroll
                for (int p = 0; p < 4; p++) {
                    int a0 = 0, a1 = 0, a2 = 0, a3 = 0;
#pragma unroll
                    for (int kh = 0; kh < 3; kh++)
#pragma unroll
                        for (int kw = 0; kw < 3; kw++) {
                            uint32_t w = wq[kh * 3 + kw];
                            a0 += __popc(win[kh][2 * p + kw] ^ w);
                            a1 += __popc(win[kh][2 * p + kw + 1] ^ w);
                            a2 += __popc(win[kh + 1][2 * p + kw] ^ w);
                            a3 += __popc(win[kh + 1][2 * p + kw + 1] ^ w);
                        }
                    int best = 288 - 2 * min(min(a0, a1), min(a2, a3));
                    unsigned long long bal = __ballot((float)best < th);
                    res[p] = make_uint2((uint32_t)bal, (uint32_t)(bal >> 32));
                }
            } else {
#pragma unroll
                for (int p = 0; p < 4; p++) {
                    int pw = 4 * pwg + p;
                    int best = -1000000;
                    if (pw < 31) {
#pragma unroll
                        for (int dy = 0; dy < 2; dy++)
#pragma unroll
                            for (int dx = 0; dx < 2; dx++) {
                                int oh = 2 * ph + dy, ow = 2 * pw + dx;
                                int acc = 0, K = 0;
                                for (int kh = 0; kh < 3; kh++) {
                                    int ih = oh - 1 + kh;
                                    if (ih < 0 || ih >= 63) continue;
                                    for (int kw = 0; kw < 3; kw++) {
                                        int iw = ow - 1 + kw;
                                        if (iw < 0 || iw >= 63) continue;
                                        acc += __popc(y1p[(n * 63 + ih) * 63 + iw] ^ wq[kh * 3 + kw]);
                                        K += 32;
                                    }
                                }
                                best = max(best, K - 2 * acc);
                            }
                    }
                    unsigned long long bal = __ballot((float)best < th);
                    res[p] = make_uint2((uint32_t)bal, (uint32_t)(bal >> 32));
                }
            }
            uint2 rr = res[0];
            if (lane == 1) rr = res[1];
            if (lane == 2) rr = res[2];
            if (lane == 3) rr = res[3];
            int pws = 4 * pwg + lane;
            if (lane < 4 && pws < 31)
                y2p[(n * 31 + ph) * 31 + pws] = rr;
        }
    }
    grid.sync();

    // ================= phase 3: bconv3 -> y3p =================
    {
        int half = wgid & 1;
        int co = half * 64 + lane;
        uint32_t wq0[9], wq1[9];
#pragma unroll
        for (int t = 0; t < 9; t++) {
            wq0[t] = w3p[(t * 2 + 0) * 128 + co];
            wq1[t] = w3p[(t * 2 + 1) * 128 + co];
        }
        float th = thr3[co];

        for (int it = (wgid >> 1); it < 64 * 15 * 8; it += (nwaves >> 1)) {
            int pwg = it & 7;
            int t2 = it >> 3;
            int ph = t2 % 15;
            int n = t2 / 15;

            unsigned long long bals[2];
            if (ph > 0 && pwg > 0) {
                int row0 = 2 * ph - 1, col0 = 4 * pwg - 1;
                uint2 win[4][6];
#pragma unroll
                for (int rr = 0; rr < 4; rr++)
#pragma unroll
                    for (int cc = 0; cc < 6; cc++)
                        win[rr][cc] = y2p[(n * 31 + row0 + rr) * 31 + min(col0 + cc, 30)];
#pragma unroll
                for (int p = 0; p < 2; p++) {
                    int a0 = 0, a1 = 0, a2 = 0, a3 = 0;
#pragma unroll
                    for (int kh = 0; kh < 3; kh++)
#pragma unroll
                        for (int kw = 0; kw < 3; kw++) {
                            int tap = kh * 3 + kw;
                            uint32_t u0 = wq0[tap], u1 = wq1[tap];
                            a0 += __popc(win[kh][2 * p + kw].x ^ u0) + __popc(win[kh][2 * p + kw].y ^ u1);
                            a1 += __popc(win[kh][2 * p + kw + 1].x ^ u0) + __popc(win[kh][2 * p + kw + 1].y ^ u1);
                            a2 += __popc(win[kh + 1][2 * p + kw].x ^ u0) + __popc(win[kh + 1][2 * p + kw].y ^ u1);
                            a3 += __popc(win[kh + 1][2 * p + kw + 1].x ^ u0) + __popc(win[kh + 1][2 * p + kw + 1].y ^ u1);
                        }
                    int best = 576 - 2 * min(min(a0, a1), min(a2, a3));
                    bals[p] = __ballot((float)best < th);
                }
            } else {
#pragma unroll
                for (int p = 0; p < 2; p++) {
                    int pw = 2 * pwg + p;
                    int best = -1000000;
                    if (pw < 15) {
#pragma unroll
                        for (int dy = 0; dy < 2; dy++)
#pragma unroll
                            for (int dx = 0; dx < 2; dx++) {
                                int oh = 2 * ph + dy, ow = 2 * pw + dx;
                                int acc = 0, K = 0;
                                for (int kh = 0; kh < 3; kh++) {
                                    int ih = oh - 1 + kh;
                                    if (ih < 0 || ih >= 31) continue;
                                    for (int kw = 0; kw < 3; kw++) {
                                        int iw = ow - 1 + kw;
                                        if (iw < 0 || iw >= 31) continue;
                                        uint2 iv = y2p[(n * 31 + ih) * 31 + iw];
                                        int tap = kh * 3 + kw;
                                        acc += __popc(iv.x ^ wq0[tap]) + __popc(iv.y ^ wq1[tap]);
                                        K += 64;
                                    }
                                }
                                best = max(best, K - 2 * acc);
                            }
                    }
                    bals[p] = __ballot((float)best < th);
                }
            }
            uint32_t val = (uint32_t)bals[0];
            if (lane == 1) val = (uint32_t)(bals[0] >> 32);
            if (lane == 2) val = (uint32_t)bals[1];
            if (lane == 3) val = (uint32_t)(bals[1] >> 32);
            int p = lane >> 1;
            int pw = 2 * pwg + p;
            if (lane < 4 && pw < 15) {
                int pixel = (n * 15 + ph) * 15 + pw;
                y3p[pixel * 4 + half * 2 + (lane & 1)] = val;
            }
        }
    }
    grid.sync();

    // ================= phase 4: bconv4 -> out (f32) =================
    {
        const uint4* y3q = (const uint4*)y3p;
        int q = wgid & 3;
        int co = q * 64 + lane;
        uint4 wq[9];
#pragma unroll
        for (int t = 0; t < 9; t++) {
            wq[t].x = w4p[(t * 4 + 0) * 256 + co];
            wq[t].y = w4p[(t * 4 + 1) * 256 + co];
            wq[t].z = w4p[(t * 4 + 2) * 256 + co];
            wq[t].w = w4p[(t * 4 + 3) * 256 + co];
        }
        float mm = m4[co], vv = v4[co], bb = b4[co];

        for (int pix = (wgid >> 2); pix < 3136; pix += (nwaves >> 2)) {
            int pw = pix % 7;
            int t2 = pix / 7;
            int ph = t2 % 7;
            int n = t2 / 7;

            int best;
            if (ph > 0 && pw > 0) {
                const uint4* p = y3q + (n * 15 + (2 * ph - 1)) * 15 + (2 * pw - 1);
                int a0 = 0, a1 = 0, a2 = 0, a3 = 0;
#pragma unroll
                for (int rr = 0; rr < 4; rr++)
#pragma unroll
                    for (int cc = 0; cc < 4; cc++) {
                        uint4 iv = p[rr * 15 + cc];
#pragma unroll
                        for (int kh = 0; kh < 3; kh++) {
                            int dy = rr - kh;
                            if (dy < 0 || dy > 1) continue;
#pragma unroll
                            for (int kw = 0; kw < 3; kw++) {
                                int dx = cc - kw;
                                if (dx < 0 || dx > 1) continue;
                                int tap = kh * 3 + kw;
                                int pc = __popc(iv.x ^ wq[tap].x) + __popc(iv.y ^ wq[tap].y)
                                       + __popc(iv.z ^ wq[tap].z) + __popc(iv.w ^ wq[tap].w);
                                if (dy == 0 && dx == 0) a0 += pc;
                                else if (dy == 0) a1 += pc;
                                else if (dx == 0) a2 += pc;
                                else a3 += pc;
                            }
                        }
                    }
                best = 1152 - 2 * min(min(a0, a1), min(a2, a3));
            } else {
                best = -1000000;
#pragma unroll
                for (int dy = 0; dy < 2; dy++)
#pragma unroll
                    for (int dx = 0; dx < 2; dx++) {
                        int oh = 2 * ph + dy, ow = 2 * pw + dx;
                        int acc = 0, K = 0;
                        for (int kh = 0; kh < 3; kh++) {
                            int ih = oh - 1 + kh;
                            if (ih < 0 || ih >= 15) continue;
                            for (int kw = 0; kw < 3; kw++) {
                                int iw = ow - 1 + kw;
                                if (iw < 0 || iw >= 15) continue;
                                uint4 iv = y3q[(n * 15 + ih) * 15 + iw];
                                int tap = kh * 3 + kw;
                                acc += __popc(iv.x ^ wq[tap].x) + __popc(iv.y ^ wq[tap].y)
                                     + __popc(iv.z ^ wq[tap].z) + __popc(iv.w ^ wq[tap].w);
                                K += 128;
                            }
                        }
                        best = max(best, K - 2 * acc);
                    }
            }
            float y = ((float)best - mm) * rsqrtf(vv + BN_EPS) + bb;
            out[pix * 256 + co] = y;
        }
    }
}

// ============================================================
// FALLBACK PATH — proven R5 kernels (used only if cooperative launch fails)
// ============================================================
__global__ void fb_pack_all(const float* __restrict__ w1, const float* __restrict__ w2,
                            const float* __restrict__ w3, const float* __restrict__ w4,
                            uint32_t* __restrict__ w1m, uint32_t* __restrict__ w2p,
                            uint32_t* __restrict__ w3p, uint32_t* __restrict__ w4p) {
    int idx = blockIdx.x * 256 + threadIdx.x;
    if (idx < 27) {
        uint32_t word = 0;
#pragma unroll
        for (int c = 0; c < 32; c++)
            word |= (uint32_t)(w1[idx * 32 + c] < 0.f) << c;
        w1m[idx] = word;
        return;
    }
    idx -= 27;
    if (idx < 576) { packw_item<32, 64>(w2, w2p, idx); return; }
    idx -= 576;
    if (idx < 2304) { packw_item<64, 128>(w3, w3p, idx); return; }
    idx -= 2304;
    if (idx < 9216) { packw_item<128, 256>(w4, w4p, idx); return; }
}

__global__ __launch_bounds__(256) void fb_conv1(const float* __restrict__ x,
                                                const uint32_t* __restrict__ w1m,
                                                const float* __restrict__ m1,
                                                const float* __restrict__ v1,
                                                const float* __restrict__ b1,
                                                uint32_t* __restrict__ y1p) {
    __shared__ float xt[34 * 104];
    int tile = blockIdx.x;
    int tx = tile & 3;
    int ty = (tile >> 2) & 3;
    int n  = tile >> 4;
    int ph0 = ty * 16, pw0 = tx * 16;
    int r0 = 2 * ph0;
    int cf0 = pw0 * 6;

    for (int i = threadIdx.x; i < 34 * 102; i += 256) {
        int r = i / 102, c = i % 102;
        int gr = r0 + r, gcf = cf0 + c;
        float vv = 0.f;
        if (gr < 128 && gcf < 384)
            vv = x[(size_t)(n * 128 + gr) * 384 + gcf];
        xt[r * 104 + c] = vv;
    }
    uint32_t um[27];
#pragma unroll
    for (int t = 0; t < 27; t++)
        um[t] = __builtin_amdgcn_readfirstlane(w1m[t]);
    __syncthreads();

    int wave = threadIdx.x >> 6, lane = threadIdx.x & 63;
    int px = lane & 15, py = (wave << 2) + (lane >> 4);
    int ph = ph0 + py, pw = pw0 + px;

    float win[48];
#pragma unroll
    for (int r = 0; r < 4; r++) {
        const float2* bp = (const float2*)&xt[(2 * py + r) * 104 + 6 * px];
#pragma unroll
        for (int q = 0; q < 6; q++) {
            float2 f2 = bp[q];
            win[r * 12 + 2 * q]     = f2.x;
            win[r * 12 + 2 * q + 1] = f2.y;
        }
    }
    uint32_t word = 0;
    for (int cg2 = 0; cg2 < 8; cg2++) {
        float a[4][4];
#pragma unroll
        for (int j = 0; j < 4; j++)
#pragma unroll
            for (int p = 0; p < 4; p++) a[j][p] = 0.f;
#pragma unroll
        for (int kh = 0; kh < 3; kh++)
#pragma unroll
            for (int kw = 0; kw < 3; kw++)
#pragma unroll
                for (int ci = 0; ci < 3; ci++) {
                    int tap = (kh * 3 + kw) * 3 + ci;
                    float x00 = win[kh * 12 + kw * 3 + ci];
                    float x01 = win[kh * 12 + (kw + 1) * 3 + ci];
                    float x10 = win[(kh + 1) * 12 + kw * 3 + ci];
                    float x11 = win[(kh + 1) * 12 + (kw + 1) * 3 + ci];
                    uint32_t mw = um[tap];
#pragma unroll
                    for (int j = 0; j < 4; j++) {
                        float w = (mw & (1u << (cg2 * 4 + j))) ? -1.f : 1.f;
                        a[j][0] += x00 * w;
                        a[j][1] += x01 * w;
                        a[j][2] += x10 * w;
                        a[j][3] += x11 * w;
                    }
                }
#pragma unroll
        for (int j = 0; j < 4; j++) {
            float mx = fmaxf(fmaxf(a[j][0], a[j][1]), fmaxf(a[j][2], a[j][3]));
            int ch = cg2 * 4 + j;
            float y = (mx - m1[ch]) * rsqrtf(v1[ch] + BN_EPS) + b1[ch];
            word |= (uint32_t)(y < 0.f) << ch;
        }
    }
    if (ph < 63 && pw < 63)
        y1p[(n * 63 + ph) * 63 + pw] = word;
}

__global__ __launch_bounds__(256) void fb_bconv2(const uint32_t* __restrict__ y1p,
                                                 const uint32_t* __restrict__ w2p,
                                                 const float* __restrict__ m,
                                                 const float* __restrict__ v,
                                                 const float* __restrict__ b,
                                                 uint2* __restrict__ y2p) {
    int gw = __builtin_amdgcn_readfirstlane(blockIdx.x * 4 + (threadIdx.x >> 6));
    int lane = threadIdx.x & 63;
    int pwg = gw & 7;
    int t = gw >> 3;
    int ph = t % 31;
    int n = t / 31;

    uint32_t wq[9];
#pragma unroll
    for (int tap = 0; tap < 9; tap++) wq[tap] = w2p[tap * 64 + lane];
    float mm = m[lane], vv = v[lane], bb = b[lane];

    uint2 res[4];
    if (ph > 0 && pwg > 0) {
        int row0 = 2 * ph - 1, col0 = 8 * pwg - 1;
        uint32_t win[4][10];
#pragma unroll
        for (int r = 0; r < 4; r++)
#pragma unroll
            for (int c = 0; c < 10; c++)
                win[r][c] = y1p[(n * 63 + row0 + r) * 63 + min(col0 + c, 62)];
#pragma unroll
        for (int p = 0; p < 4; p++) {
            int a0 = 0, a1 = 0, a2 = 0, a3 = 0;
#pragma unroll
            for (int kh = 0; kh < 3; kh++)
#pragma unroll
                for (int kw = 0; kw < 3; kw++) {
                    uint32_t w = wq[kh * 3 + kw];
                    a0 += __popc(win[kh][2 * p + kw] ^ w);
                    a1 += __popc(win[kh][2 * p + kw + 1] ^ w);
                    a2 += __popc(win[kh + 1][2 * p + kw] ^ w);
                    a3 += __popc(win[kh + 1][2 * p + kw + 1] ^ w);
                }
            int best = 288 - 2 * min(min(a0, a1), min(a2, a3));
            float y = ((float)best - mm) * rsqrtf(vv + BN_EPS) + bb;
            unsigned long long bal = __ballot(y < 0.f);
            res[p] = make_uint2((uint32_t)bal, (uint32_t)(bal >> 32));
        }
    } else {
#pragma unroll
        for (int p = 0; p < 4; p++) {
            int pw = 4 * pwg + p;
            int best = -1000000;
            if (pw < 31) {
#pragma unroll
                for (int dy = 0; dy < 2; dy++)
#pragma unroll
                    for (int dx = 0; dx < 2; dx++) {
                        int oh = 2 * ph + dy, ow = 2 * pw + dx;
                        int acc = 0, K = 0;
                        for (int kh = 0; kh < 3; kh++) {
                            int ih = oh - 1 + kh;
                            if (ih < 0 || ih >= 63) continue;
                            for (int kw = 0; kw < 3; kw++) {
                                int iw = ow - 1 + kw;
                                if (iw < 0 || iw >= 63) continue;
                                acc += __popc(y1p[(n * 63 + ih) * 63 + iw] ^ wq[kh * 3 + kw]);
                                K += 32;
                            }
                        }
                        best = max(best, K - 2 * acc);
                    }
            }
            float y = ((float)best - mm) * rsqrtf(vv + BN_EPS) + bb;
            unsigned long long bal = __ballot(y < 0.f);
            res[p] = make_uint2((uint32_t)bal, (uint32_t)(bal >> 32));
        }
    }
    uint2 rr = res[0];
    if (lane == 1) rr = res[1];
    if (lane == 2) rr = res[2];
    if (lane == 3) rr = res[3];
    int pws = 4 * pwg + lane;
    if (lane < 4 && pws < 31)
        y2p[(n * 31 + ph) * 31 + pws] = rr;
}

__global__ __launch_bounds__(256) void fb_bconv3(const uint2* __restrict__ y2p,
                                                 const uint32_t* __restrict__ w3p,
                                                 const float* __restrict__ m,
                                                 const float* __restrict__ v,
                                                 const float* __restrict__ b,
                                                 uint32_t* __restrict__ y3p) {
    int gw = __builtin_amdgcn_readfirstlane(blockIdx.x * 4 + (threadIdx.x >> 6));
    int lane = threadIdx.x & 63;
    int half = gw & 1;
    int t = gw >> 1;
    int pwg = t & 7;
    t >>= 3;
    int ph = t % 15;
    int n = t / 15;
    int co = half * 64 + lane;

    uint32_t wq0[9], wq1[9];
#pragma unroll
    for (int tap = 0; tap < 9; tap++) {
        wq0[tap] = w3p[(tap * 2 + 0) * 128 + co];
        wq1[tap] = w3p[(tap * 2 + 1) * 128 + co];
    }
    float mm = m[co], vv = v[co], bb = b[co];

    unsigned long long bals[2];
    if (ph > 0 && pwg > 0) {
        int row0 = 2 * ph - 1, col0 = 4 * pwg - 1;
        uint2 win[4][6];
#pragma unroll
        for (int r = 0; r < 4; r++)
#pragma unroll
            for (int c = 0; c < 6; c++)
                win[r][c] = y2p[(n * 31 + row0 + r) * 31 + min(col0 + c, 30)];
#pragma unroll
        for (int p = 0; p < 2; p++) {
            int a0 = 0, a1 = 0, a2 = 0, a3 = 0;
#pragma unroll
            for (int kh = 0; kh < 3; kh++)
#pragma unroll
                for (int kw = 0; kw < 3; kw++) {
                    int tap = kh * 3 + kw;
                    uint32_t u0 = wq0[tap], u1 = wq1[tap];
                    a0 += __popc(win[kh][2 * p + kw].x ^ u0) + __popc(win[kh][2 * p + kw].y ^ u1);
                    a1 += __popc(win[kh][2 * p + kw + 1].x ^ u0) + __popc(win[kh][2 * p + kw + 1].y ^ u1);
                    a2 += __popc(win[kh + 1][2 * p + kw].x ^ u0) + __popc(win[kh + 1][2 * p + kw].y ^ u1);
                    a3 += __popc(win[kh + 1][2 * p + kw + 1].x ^ u0) + __popc(win[kh + 1][2 * p + kw + 1].y ^ u1);
                }
            int best = 576 - 2 * min(min(a0, a1), min(a2, a3));
            float y = ((float)best - mm) * rsqrtf(vv + BN_EPS) + bb;
            bals[p] = __ballot(y < 0.f);
        }
    } else {
#pragma unroll
        for (int p = 0; p < 2; p++) {
            int pw = 2 * pwg + p;
            int best = -1000000;
            if (pw < 15) {
#pragma unroll
                for (int dy = 0; dy < 2; dy++)
#pragma unroll
                    for (int dx = 0; dx < 2; dx++) {
                        int oh = 2 * ph + dy, ow = 2 * pw + dx;
                        int acc = 0, K = 0;
                        for (int kh = 0; kh < 3; kh++) {
                            int ih = oh - 1 + kh;
                            if (ih < 0 || ih >= 31) continue;
                            for (int kw = 0; kw < 3; kw++) {
                                int iw = ow - 1 + kw;
                                if (iw < 0 || iw >= 31) continue;
                                uint2 iv = y2p[(n * 31 + ih) * 31 + iw];
                                int tap = kh * 3 + kw;
                                acc += __popc(iv.x ^ wq0[tap]) + __popc(iv.y ^ wq1[tap]);
                                K += 64;
                            }
                        }
                        best = max(best, K - 2 * acc);
                    }
            }
            float y = ((float)best - mm) * rsqrtf(vv + BN_EPS) + bb;
            bals[p] = __ballot(y < 0.f);
        }
    }
    uint32_t val = (uint32_t)bals[0];
    if (lane == 1) val = (uint32_t)(bals[0] >> 32);
    if (lane == 2) val = (uint32_t)bals[1];
    if (lane == 3) val = (uint32_t)(bals[1] >> 32);
    int p = lane >> 1;
    int pw = 2 * pwg + p;
    if (lane < 4 && pw < 15) {
        int pixel = (n * 15 + ph) * 15 + pw;
        y3p[pixel * 4 + half * 2 + (lane & 1)] = val;
    }
}

__global__ __launch_bounds__(256) void fb_bconv4(const uint4* __restrict__ y3p,
                                                 const uint32_t* __restrict__ w4p,
                                                 const float* __restrict__ m,
                                                 const float* __restrict__ v,
                                                 const float* __restrict__ b,
                                                 float* __restrict__ out) {
    int pixel = blockIdx.x;
    int lane = threadIdx.x & 63;
    int co = (threadIdx.x >> 6) * 64 + lane;
    int pw = pixel % 7;
    int t = pixel / 7;
    int ph = t % 7;
    int n = t / 7;

    uint4 wq[9];
#pragma unroll
    for (int tap = 0; tap < 9; tap++) {
        wq[tap].x = w4p[(tap * 4 + 0) * 256 + co];
        wq[tap].y = w4p[(tap * 4 + 1) * 256 + co];
        wq[tap].z = w4p[(tap * 4 + 2) * 256 + co];
        wq[tap].w = w4p[(tap * 4 + 3) * 256 + co];
    }
    int best;
    if (ph > 0 && pw > 0) {
        const uint4* p = y3p + (n * 15 + (2 * ph - 1)) * 15 + (2 * pw - 1);
        int a0 = 0, a1 = 0, a2 = 0, a3 = 0;
#pragma unroll
        for (int rr = 0; rr < 4; rr++)
#pragma unroll
            for (int cc = 0; cc < 4; cc++) {
                uint4 iv = p[rr * 15 + cc];
#pragma unroll
                for (int kh = 0; kh < 3; kh++) {
                    int dy = rr - kh;
                    if (dy < 0 || dy > 1) continue;
#pragma unroll
                    for (int kw = 0; kw < 3; kw++) {
                        int dx = cc - kw;
                        if (dx < 0 || dx > 1) continue;
                        int tap = kh * 3 + kw;
                        int pc = __popc(iv.x ^ wq[tap].x) + __popc(iv.y ^ wq[tap].y)
                               + __popc(iv.z ^ wq[tap].z) + __popc(iv.w ^ wq[tap].w);
                        if (dy == 0 && dx == 0) a0 += pc;
                        else if (dy == 0) a1 += pc;
                        else if (dx == 0) a2 += pc;
                        else a3 += pc;
                    }
                }
            }
        best = 1152 - 2 * min(min(a0, a1), min(a2, a3));
    } else {
        best = -1000000;
#pragma unroll
        for (int dy = 0; dy < 2; dy++)
#pragma unroll
            for (int dx = 0; dx < 2; dx++) {
                int oh = 2 * ph + dy, ow = 2 * pw + dx;
                int acc = 0, K = 0;
                for (int kh = 0; kh < 3; kh++) {
                    int ih = oh - 1 + kh;
                    if (ih < 0 || ih >= 15) continue;
                    for (int kw = 0; kw < 3; kw++) {
                        int iw = ow - 1 + kw;
                        if (iw < 0 || iw >= 15) continue;
                        uint4 iv = y3p[(n * 15 + ih) * 15 + iw];
                        int tap = kh * 3 + kw;
                        acc += __popc(iv.x ^ wq[tap].x) + __popc(iv.y ^ wq[tap].y)
                             + __popc(iv.z ^ wq[tap].z) + __popc(iv.w ^ wq[tap].w);
                        K += 128;
                    }
                }
                best = max(best, K - 2 * acc);
            }
    }
    float y = ((float)best - m[co]) * rsqrtf(v[co] + BN_EPS) + b[co];
    out[pixel * 256 + co] = y;
}

extern "C" void kernel_launch(void* const* d_in, const int* in_sizes, int n_in,
                              void* d_out, int out_size, void* d_ws, size_t ws_size,
                              hipStream_t stream) {
    const float* x  = (const float*)d_in[0];
    const float* w1 = (const float*)d_in[1];
    const float* m1 = (const float*)d_in[2];
    const float* v1 = (const float*)d_in[3];
    const float* b1 = (const float*)d_in[4];
    const float* w2 = (const float*)d_in[5];
    const float* m2 = (const float*)d_in[6];
    const float* v2 = (const float*)d_in[7];
    const float* b2 = (const float*)d_in[8];
    const float* w3 = (const float*)d_in[9];
    const float* m3 = (const float*)d_in[10];
    const float* v3 = (const float*)d_in[11];
    const float* b3 = (const float*)d_in[12];
    const float* w4 = (const float*)d_in[13];
    const float* m4 = (const float*)d_in[14];
    const float* v4 = (const float*)d_in[15];
    const float* b4 = (const float*)d_in[16];
    float* outp = (float*)d_out;

    char* ws = (char*)d_ws;
    size_t off = 0;
    auto take = [&](size_t bytes) -> char* {
        char* p = ws + off;
        off += (bytes + 255) & ~(size_t)255;
        return p;
    };
    uint32_t* y1p  = (uint32_t*)take((size_t)64 * 63 * 63 * 4);
    uint2*    y2p  = (uint2*)take((size_t)64 * 31 * 31 * 8);
    uint32_t* y3p  = (uint32_t*)take((size_t)64 * 15 * 15 * 16);
    uint32_t* w1m  = (uint32_t*)take(27 * 4);
    float*    thr1 = (float*)take(32 * 4);
    uint32_t* w2p  = (uint32_t*)take(576 * 4);
    float*    thr2 = (float*)take(64 * 4);
    uint32_t* w3p  = (uint32_t*)take(2304 * 4);
    float*    thr3 = (float*)take(128 * 4);
    uint32_t* w4p  = (uint32_t*)take(9216 * 4);

    // Size the cooperative grid from the occupancy the runtime will enforce.
    int maxb = 0;
    hipError_t oe = hipOccupancyMaxActiveBlocksPerMultiprocessor(&maxb, fused, 256, 0);
    if (oe != hipSuccess || maxb < 1) maxb = 1;
    int nblk = maxb * 256;              // 256 CUs on MI355X
    if (nblk > 4096) nblk = 4096;

    void* args[] = {
        (void*)&x,  (void*)&w1, (void*)&w2, (void*)&w3, (void*)&w4,
        (void*)&m1, (void*)&v1, (void*)&b1,
        (void*)&m2, (void*)&v2, (void*)&b2,
        (void*)&m3, (void*)&v3, (void*)&b3,
        (void*)&m4, (void*)&v4, (void*)&b4,
        (void*)&w1m, (void*)&thr1, (void*)&w2p, (void*)&thr2,
        (void*)&w3p, (void*)&thr3, (void*)&w4p,
        (void*)&y1p, (void*)&y2p, (void*)&y3p, (void*)&outp
    };
    hipError_t le = hipLaunchCooperativeKernel((const void*)fused, dim3(nblk), dim3(256),
                                               args, 0, stream);
    if (le != hipSuccess) {
        // Fallback: proven 5-kernel path (R5).
        fb_pack_all<<<(12123 + 255) / 256, 256, 0, stream>>>(w1, w2, w3, w4, w1m, w2p, w3p, w4p);
        fb_conv1<<<64 * 16, 256, 0, stream>>>(x, w1m, m1, v1, b1, y1p);
        fb_bconv2<<<(64 * 31 * 8) / 4, 256, 0, stream>>>(y1p, w2p, m2, v2, b2, y2p);
        fb_bconv3<<<(64 * 15 * 8 * 2) / 4, 256, 0, stream>>>(y2p, w3p, m3, v3, b3, y3p);
        fb_bconv4<<<64 * 7 * 7, 256, 0, stream>>>((const uint4*)y3p, w4p, m4, v4, b4, outp);
    }
}

// Round 8
// 218.798 us; speedup vs baseline: 2.4387x; 2.4387x over previous
//
#include <hip/hip_runtime.h>
#include <stdint.h>
#include <math.h>

#define BN_EPS 1e-3f

__device__ __forceinline__ uint32_t rfl_u32(uint32_t v) {
    return __builtin_amdgcn_readfirstlane(v);
}

// bit-pack weight signs: bit=1 <=> w<0; layout [(tap*CINW+wi)][COUT]
template <int CIN, int COUT>
__device__ inline void packw_item(const float* __restrict__ w, uint32_t* __restrict__ wp, int idx) {
    const int CINW = CIN / 32;
    int co = idx % COUT;
    int t2 = idx / COUT;
    int wi = t2 % CINW;
    int tap = t2 / CINW;
    uint32_t word = 0;
#pragma unroll
    for (int bb = 0; bb < 32; bb++) {
        float val = w[((tap * CIN) + wi * 32 + bb) * COUT + co];
        word |= (uint32_t)(val < 0.f) << bb;
    }
    wp[idx] = word;
}

// sign(bn(v)) < 0  <=>  v < m - b*sqrt(var+eps)   (rsqrt > 0 always)
__device__ inline float mk_thr(const float* m, const float* v, const float* b, int c) {
    return (float)((double)m[c] - (double)b[c] * sqrt((double)v[c] + (double)BN_EPS));
}

// ============================================================
// Weight prep: w1 masks, packed w2/w3/w4, thresholds 1..3
// items: 27 + 32 + 576 + 64 + 2304 + 128 + 9216 = 12347
// ============================================================
__global__ void pack_all(const float* __restrict__ w1, const float* __restrict__ w2,
                         const float* __restrict__ w3, const float* __restrict__ w4,
                         const float* __restrict__ m1, const float* __restrict__ v1,
                         const float* __restrict__ b1,
                         const float* __restrict__ m2, const float* __restrict__ v2,
                         const float* __restrict__ b2,
                         const float* __restrict__ m3, const float* __restrict__ v3,
                         const float* __restrict__ b3,
                         uint32_t* __restrict__ w1m, float* __restrict__ thr1,
                         uint32_t* __restrict__ w2p, float* __restrict__ thr2,
                         uint32_t* __restrict__ w3p, float* __restrict__ thr3,
                         uint32_t* __restrict__ w4p) {
    int j = blockIdx.x * 256 + threadIdx.x;
    if (j < 27) {
        uint32_t word = 0;
#pragma unroll
        for (int c = 0; c < 32; c++)
            word |= (uint32_t)(w1[j * 32 + c] < 0.f) << c;
        w1m[j] = word;
    } else if ((j -= 27) < 32) {
        thr1[j] = mk_thr(m1, v1, b1, j);
    } else if ((j -= 32) < 576) {
        packw_item<32, 64>(w2, w2p, j);
    } else if ((j -= 576) < 64) {
        thr2[j] = mk_thr(m2, v2, b2, j);
    } else if ((j -= 64) < 2304) {
        packw_item<64, 128>(w3, w3p, j);
    } else if ((j -= 2304) < 128) {
        thr3[j] = mk_thr(m3, v3, b3, j);
    } else if ((j -= 128) < 9216) {
        packw_item<128, 256>(w4, w4p, j);
    }
}

// ============================================================
// Layer 1: conv(x, sign(w1), VALID) + maxpool2 + bn + sign -> packed u32.
// Block 256, tile 16x16 pooled pixels. Thread = 1 pooled pixel x 32 ch.
// Weight = SGPR +-1.0f (readfirstlane-forced cselect) -> 1 v_fmac per MAC.
// 4 channel-groups of 8 (a[8][4] accumulators, win[48] stays in VGPRs).
// ============================================================
__global__ __launch_bounds__(256, 4) void conv1_k(const float* __restrict__ x,
                                                  const uint32_t* __restrict__ w1m,
                                                  const float* __restrict__ thr1,
                                                  uint32_t* __restrict__ y1p) {
    __shared__ float xt[34 * 104];     // 34 input rows x 102 col-floats (pad 104)

    int tile = blockIdx.x;
    int tx = tile & 3;
    int ty = (tile >> 2) & 3;
    int n  = tile >> 4;
    int ph0 = ty * 16, pw0 = tx * 16;
    int r0 = 2 * ph0;
    int cf0 = pw0 * 6;                 // col-float origin (x row = 384 floats)

    for (int i = threadIdx.x; i < 34 * 102; i += 256) {
        int r = i / 102, c = i % 102;
        int gr = r0 + r, gcf = cf0 + c;
        float vv = 0.f;
        if (gr < 128 && gcf < 384)
            vv = x[(size_t)(n * 128 + gr) * 384 + gcf];
        xt[r * 104 + c] = vv;
    }

    uint32_t um[27];
#pragma unroll
    for (int t = 0; t < 27; t++) um[t] = rfl_u32(w1m[t]);
    float th[32];
#pragma unroll
    for (int c = 0; c < 32; c++)
        th[c] = __uint_as_float(rfl_u32(((const uint32_t*)thr1)[c]));

    __syncthreads();

    int wave = threadIdx.x >> 6, lane = threadIdx.x & 63;
    int px = lane & 15, py = (wave << 2) + (lane >> 4);
    int ph = ph0 + py, pw = pw0 + px;

    // 4x4x3 input window in regs (float2 LDS reads, 8B aligned)
    float win[48];
#pragma unroll
    for (int r = 0; r < 4; r++) {
        const float2* bp = (const float2*)&xt[(2 * py + r) * 104 + 6 * px];
#pragma unroll
        for (int q = 0; q < 6; q++) {
            float2 f2 = bp[q];
            win[r * 12 + 2 * q]     = f2.x;
            win[r * 12 + 2 * q + 1] = f2.y;
        }
    }

    uint32_t word = 0;
#pragma unroll
    for (int cg = 0; cg < 4; cg++) {            // 8 channels per group
        float a[8][4];
#pragma unroll
        for (int j = 0; j < 8; j++)
#pragma unroll
            for (int p = 0; p < 4; p++) a[j][p] = 0.f;
#pragma unroll
        for (int kh = 0; kh < 3; kh++)
#pragma unroll
            for (int kw = 0; kw < 3; kw++)
#pragma unroll
                for (int ci = 0; ci < 3; ci++) {
                    int tap = (kh * 3 + kw) * 3 + ci;
                    float x00 = win[kh * 12 + kw * 3 + ci];
                    float x01 = win[kh * 12 + (kw + 1) * 3 + ci];
                    float x10 = win[(kh + 1) * 12 + kw * 3 + ci];
                    float x11 = win[(kh + 1) * 12 + (kw + 1) * 3 + ci];
                    uint32_t mw = um[tap] >> (cg * 8);
#pragma unroll
                    for (int j = 0; j < 8; j++) {
                        // guaranteed-SGPR +-1.0f: scalar cselect, free vs VALU
                        float w = __uint_as_float(rfl_u32(
                            ((mw >> j) & 1u) ? 0xbf800000u : 0x3f800000u));
                        a[j][0] += x00 * w;
                        a[j][1] += x01 * w;
                        a[j][2] += x10 * w;
                        a[j][3] += x11 * w;
                    }
                }
#pragma unroll
        for (int j = 0; j < 8; j++) {
            float mx = fmaxf(fmaxf(a[j][0], a[j][1]), fmaxf(a[j][2], a[j][3]));
            int ch = cg * 8 + j;
            word |= (uint32_t)(mx < th[ch]) << ch;
        }
    }

    if (ph < 63 && pw < 63)
        y1p[(n * 63 + ph) * 63 + pw] = word;
}

// ============================================================
// Layer 2: bconv(SAME, 63x63, CIN=32) + maxpool2 + bn + sign -> packed
// One wave per 4-pixel row group; lane = co. Window = 4x10 uniform words.
// ============================================================
__global__ __launch_bounds__(256) void bconv2(const uint32_t* __restrict__ y1p,
                                              const uint32_t* __restrict__ w2p,
                                              const float* __restrict__ thr2,
                                              uint2* __restrict__ y2p) {
    int gw = __builtin_amdgcn_readfirstlane(blockIdx.x * 4 + (threadIdx.x >> 6));
    int lane = threadIdx.x & 63;
    int pwg = gw & 7;          // pixel group: pw = 4*pwg + p
    int t = gw >> 3;
    int ph = t % 31;
    int n = t / 31;

    uint32_t wq[9];
#pragma unroll
    for (int tap = 0; tap < 9; tap++) wq[tap] = w2p[tap * 64 + lane];
    float th = thr2[lane];

    uint2 res[4];
    if (ph > 0 && pwg > 0) {
        int row0 = 2 * ph - 1, col0 = 8 * pwg - 1;
        uint32_t win[4][10];
#pragma unroll
        for (int r = 0; r < 4; r++)
#pragma unroll
            for (int c = 0; c < 10; c++)
                win[r][c] = y1p[(n * 63 + row0 + r) * 63 + min(col0 + c, 62)];
#pragma unroll
        for (int p = 0; p < 4; p++) {
            int a0 = 0, a1 = 0, a2 = 0, a3 = 0;
#pragma unroll
            for (int kh = 0; kh < 3; kh++)
#pragma unroll
                for (int kw = 0; kw < 3; kw++) {
                    uint32_t w = wq[kh * 3 + kw];
                    a0 += __popc(win[kh][2 * p + kw] ^ w);
                    a1 += __popc(win[kh][2 * p + kw + 1] ^ w);
                    a2 += __popc(win[kh + 1][2 * p + kw] ^ w);
                    a3 += __popc(win[kh + 1][2 * p + kw + 1] ^ w);
                }
            int best = 288 - 2 * min(min(a0, a1), min(a2, a3));
            unsigned long long bal = __ballot((float)best < th);
            res[p] = make_uint2((uint32_t)bal, (uint32_t)(bal >> 32));
        }
    } else {
#pragma unroll
        for (int p = 0; p < 4; p++) {
            int pw = 4 * pwg + p;
            int best = -1000000;
            if (pw < 31) {
#pragma unroll
                for (int dy = 0; dy < 2; dy++)
#pragma unroll
                    for (int dx = 0; dx < 2; dx++) {
                        int oh = 2 * ph + dy, ow = 2 * pw + dx;
                        int acc = 0, K = 0;
                        for (int kh = 0; kh < 3; kh++) {
                            int ih = oh - 1 + kh;
                            if (ih < 0 || ih >= 63) continue;
                            for (int kw = 0; kw < 3; kw++) {
                                int iw = ow - 1 + kw;
                                if (iw < 0 || iw >= 63) continue;
                                acc += __popc(y1p[(n * 63 + ih) * 63 + iw] ^ wq[kh * 3 + kw]);
                                K += 32;
                            }
                        }
                        best = max(best, K - 2 * acc);
                    }
            }
            unsigned long long bal = __ballot((float)best < th);
            res[p] = make_uint2((uint32_t)bal, (uint32_t)(bal >> 32));
        }
    }
    uint2 rr = res[0];
    if (lane == 1) rr = res[1];
    if (lane == 2) rr = res[2];
    if (lane == 3) rr = res[3];
    int pws = 4 * pwg + lane;
    if (lane < 4 && pws < 31)
        y2p[(n * 31 + ph) * 31 + pws] = rr;
}

// ============================================================
// Layer 3: bconv(SAME, 31x31, CIN=64) + maxpool2 + bn + sign -> packed
// Wave per (2-pixel group, co-half). Window = 4x6 uint2 uniform words.
// ============================================================
__global__ __launch_bounds__(256) void bconv3(const uint2* __restrict__ y2p,
                                              const uint32_t* __restrict__ w3p,
                                              const float* __restrict__ thr3,
                                              uint32_t* __restrict__ y3p) {
    int gw = __builtin_amdgcn_readfirstlane(blockIdx.x * 4 + (threadIdx.x >> 6));
    int lane = threadIdx.x & 63;
    int half = gw & 1;
    int t = gw >> 1;
    int pwg = t & 7;           // pw = 2*pwg + p
    t >>= 3;
    int ph = t % 15;
    int n = t / 15;
    int co = half * 64 + lane;

    uint32_t wq0[9], wq1[9];
#pragma unroll
    for (int tap = 0; tap < 9; tap++) {
        wq0[tap] = w3p[(tap * 2 + 0) * 128 + co];
        wq1[tap] = w3p[(tap * 2 + 1) * 128 + co];
    }
    float th = thr3[co];

    unsigned long long bals[2];
    if (ph > 0 && pwg > 0) {
        int row0 = 2 * ph - 1, col0 = 4 * pwg - 1;
        uint2 win[4][6];
#pragma unroll
        for (int r = 0; r < 4; r++)
#pragma unroll
            for (int c = 0; c < 6; c++)
                win[r][c] = y2p[(n * 31 + row0 + r) * 31 + min(col0 + c, 30)];
#pragma unroll
        for (int p = 0; p < 2; p++) {
            int a0 = 0, a1 = 0, a2 = 0, a3 = 0;
#pragma unroll
            for (int kh = 0; kh < 3; kh++)
#pragma unroll
                for (int kw = 0; kw < 3; kw++) {
                    int tap = kh * 3 + kw;
                    uint32_t u0 = wq0[tap], u1 = wq1[tap];
                    a0 += __popc(win[kh][2 * p + kw].x ^ u0) + __popc(win[kh][2 * p + kw].y ^ u1);
                    a1 += __popc(win[kh][2 * p + kw + 1].x ^ u0) + __popc(win[kh][2 * p + kw + 1].y ^ u1);
                    a2 += __popc(win[kh + 1][2 * p + kw].x ^ u0) + __popc(win[kh + 1][2 * p + kw].y ^ u1);
                    a3 += __popc(win[kh + 1][2 * p + kw + 1].x ^ u0) + __popc(win[kh + 1][2 * p + kw + 1].y ^ u1);
                }
            int best = 576 - 2 * min(min(a0, a1), min(a2, a3));
            bals[p] = __ballot((float)best < th);
        }
    } else {
#pragma unroll
        for (int p = 0; p < 2; p++) {
            int pw = 2 * pwg + p;
            int best = -1000000;
            if (pw < 15) {
#pragma unroll
                for (int dy = 0; dy < 2; dy++)
#pragma unroll
                    for (int dx = 0; dx < 2; dx++) {
                        int oh = 2 * ph + dy, ow = 2 * pw + dx;
                        int acc = 0, K = 0;
                        for (int kh = 0; kh < 3; kh++) {
                            int ih = oh - 1 + kh;
                            if (ih < 0 || ih >= 31) continue;
                            for (int kw = 0; kw < 3; kw++) {
                                int iw = ow - 1 + kw;
                                if (iw < 0 || iw >= 31) continue;
                                uint2 iv = y2p[(n * 31 + ih) * 31 + iw];
                                int tap = kh * 3 + kw;
                                acc += __popc(iv.x ^ wq0[tap]) + __popc(iv.y ^ wq1[tap]);
                                K += 64;
                            }
                        }
                        best = max(best, K - 2 * acc);
                    }
            }
            bals[p] = __ballot((float)best < th);
        }
    }
    uint32_t val = (uint32_t)bals[0];
    if (lane == 1) val = (uint32_t)(bals[0] >> 32);
    if (lane == 2) val = (uint32_t)bals[1];
    if (lane == 3) val = (uint32_t)(bals[1] >> 32);
    int p = lane >> 1;
    int pw = 2 * pwg + p;
    if (lane < 4 && pw < 15) {
        int pixel = (n * 15 + ph) * 15 + pw;
        y3p[pixel * 4 + half * 2 + (lane & 1)] = val;
    }
}

// ============================================================
// Layer 4: bconv(SAME, 15x15, CIN=128) + maxpool2 + bn -> f32 out
// Block per pixel; wave = one co-quad (co = wave*64 + lane).
// ============================================================
__global__ __launch_bounds__(256) void bconv4(const uint4* __restrict__ y3p,
                                              const uint32_t* __restrict__ w4p,
                                              const float* __restrict__ m,
                                              const float* __restrict__ v,
                                              const float* __restrict__ b,
                                              float* __restrict__ out) {
    int pixel = blockIdx.x;
    int lane = threadIdx.x & 63;
    int co = (threadIdx.x >> 6) * 64 + lane;
    int pw = pixel % 7;
    int t = pixel / 7;
    int ph = t % 7;
    int n = t / 7;

    uint4 wq[9];
#pragma unroll
    for (int tap = 0; tap < 9; tap++) {
        wq[tap].x = w4p[(tap * 4 + 0) * 256 + co];
        wq[tap].y = w4p[(tap * 4 + 1) * 256 + co];
        wq[tap].z = w4p[(tap * 4 + 2) * 256 + co];
        wq[tap].w = w4p[(tap * 4 + 3) * 256 + co];
    }
    int best;
    if (ph > 0 && pw > 0) {
        const uint4* p = y3p + (n * 15 + (2 * ph - 1)) * 15 + (2 * pw - 1);
        int a0 = 0, a1 = 0, a2 = 0, a3 = 0;
#pragma unroll
        for (int rr = 0; rr < 4; rr++)
#pragma unroll
            for (int cc = 0; cc < 4; cc++) {
                uint4 iv = p[rr * 15 + cc];
#pragma unroll
                for (int kh = 0; kh < 3; kh++) {
                    int dy = rr - kh;
                    if (dy < 0 || dy > 1) continue;
#pragma unroll
                    for (int kw = 0; kw < 3; kw++) {
                        int dx = cc - kw;
                        if (dx < 0 || dx > 1) continue;
                        int tap = kh * 3 + kw;
                        int pc = __popc(iv.x ^ wq[tap].x) + __popc(iv.y ^ wq[tap].y)
                               + __popc(iv.z ^ wq[tap].z) + __popc(iv.w ^ wq[tap].w);
                        if (dy == 0 && dx == 0) a0 += pc;
                        else if (dy == 0) a1 += pc;
                        else if (dx == 0) a2 += pc;
                        else a3 += pc;
                    }
                }
            }
        best = 1152 - 2 * min(min(a0, a1), min(a2, a3));
    } else {
        best = -1000000;
#pragma unroll
        for (int dy = 0; dy < 2; dy++)
#pragma unroll
            for (int dx = 0; dx < 2; dx++) {
                int oh = 2 * ph + dy, ow = 2 * pw + dx;
                int acc = 0, K = 0;
                for (int kh = 0; kh < 3; kh++) {
                    int ih = oh - 1 + kh;
                    if (ih < 0 || ih >= 15) continue;
                    for (int kw = 0; kw < 3; kw++) {
                        int iw = ow - 1 + kw;
                        if (iw < 0 || iw >= 15) continue;
                        uint4 iv = y3p[(n * 15 + ih) * 15 + iw];
                        int tap = kh * 3 + kw;
                        acc += __popc(iv.x ^ wq[tap].x) + __popc(iv.y ^ wq[tap].y)
                             + __popc(iv.z ^ wq[tap].z) + __popc(iv.w ^ wq[tap].w);
                        K += 128;
                    }
                }
                best = max(best, K - 2 * acc);
            }
    }
    float y = ((float)best - m[co]) * rsqrtf(v[co] + BN_EPS) + b[co];
    out[pixel * 256 + co] = y;
}

extern "C" void kernel_launch(void* const* d_in, const int* in_sizes, int n_in,
                              void* d_out, int out_size, void* d_ws, size_t ws_size,
                              hipStream_t stream) {
    const float* x  = (const float*)d_in[0];
    const float* w1 = (const float*)d_in[1];
    const float* m1 = (const float*)d_in[2];
    const float* v1 = (const float*)d_in[3];
    const float* b1 = (const float*)d_in[4];
    const float* w2 = (const float*)d_in[5];
    const float* m2 = (const float*)d_in[6];
    const float* v2 = (const float*)d_in[7];
    const float* b2 = (const float*)d_in[8];
    const float* w3 = (const float*)d_in[9];
    const float* m3 = (const float*)d_in[10];
    const float* v3 = (const float*)d_in[11];
    const float* b3 = (const float*)d_in[12];
    const float* w4 = (const float*)d_in[13];
    const float* m4 = (const float*)d_in[14];
    const float* v4 = (const float*)d_in[15];
    const float* b4 = (const float*)d_in[16];
    float* outp = (float*)d_out;

    char* ws = (char*)d_ws;
    size_t off = 0;
    auto take = [&](size_t bytes) -> char* {
        char* p = ws + off;
        off += (bytes + 255) & ~(size_t)255;
        return p;
    };
    uint32_t* y1p  = (uint32_t*)take((size_t)64 * 63 * 63 * 4);
    uint2*    y2p  = (uint2*)take((size_t)64 * 31 * 31 * 8);
    uint32_t* y3p  = (uint32_t*)take((size_t)64 * 15 * 15 * 16);
    uint32_t* w1m  = (uint32_t*)take(27 * 4);
    float*    thr1 = (float*)take(32 * 4);
    uint32_t* w2p  = (uint32_t*)take(576 * 4);
    float*    thr2 = (float*)take(64 * 4);
    uint32_t* w3p  = (uint32_t*)take(2304 * 4);
    float*    thr3 = (float*)take(128 * 4);
    uint32_t* w4p  = (uint32_t*)take(9216 * 4);

    pack_all<<<(12347 + 255) / 256, 256, 0, stream>>>(
        w1, w2, w3, w4, m1, v1, b1, m2, v2, b2, m3, v3, b3,
        w1m, thr1, w2p, thr2, w3p, thr3, w4p);

    conv1_k<<<64 * 16, 256, 0, stream>>>(x, w1m, thr1, y1p);

    bconv2<<<(64 * 31 * 8) / 4, 256, 0, stream>>>(y1p, w2p, thr2, y2p);

    bconv3<<<(64 * 15 * 8 * 2) / 4, 256, 0, stream>>>(y2p, w3p, thr3, y3p);

    bconv4<<<64 * 7 * 7, 256, 0, stream>>>((const uint4*)y3p, w4p, m4, v4, b4, outp);
}

// Round 9
// 185.166 us; speedup vs baseline: 2.8816x; 1.1816x over previous
//
#include <hip/hip_runtime.h>
#include <stdint.h>
#include <math.h>

#define BN_EPS 1e-3f

// bit-pack weight signs: bit=1 <=> w<0; layout [(tap*CINW+wi)][COUT]
template <int CIN, int COUT>
__device__ inline void packw_item(const float* __restrict__ w, uint32_t* __restrict__ wp, int idx) {
    const int CINW = CIN / 32;
    int co = idx % COUT;
    int t2 = idx / COUT;
    int wi = t2 % CINW;
    int tap = t2 / CINW;
    uint32_t word = 0;
#pragma unroll
    for (int bb = 0; bb < 32; bb++) {
        float val = w[((tap * CIN) + wi * 32 + bb) * COUT + co];
        word |= (uint32_t)(val < 0.f) << bb;
    }
    wp[idx] = word;
}

// sign(bn(v)) < 0  <=>  v < m - b*sqrt(var+eps)   (rsqrt > 0 always)
__device__ inline float mk_thr(const float* m, const float* v, const float* b, int c) {
    return (float)((double)m[c] - (double)b[c] * sqrt((double)v[c] + (double)BN_EPS));
}

// ============================================================
// Kernel 1 = conv1 (blocks 0..1023) + weight-prep for layers 2-4
// (blocks 1024..1071). Pack outputs are consumed only by LATER kernels,
// so stream order covers the dependency. conv1 builds its own w1 masks
// (via __ballot) and thresholds (LDS), so no intra-kernel race.
//
// conv1: conv(x, sign(w1), VALID) + maxpool2 + bn + sign -> packed u32.
// Block 256, tile 16x16 pooled pixels, thread = 1 pooled pixel x 32 ch.
// 2 channel-groups of 16: a[16][4] accumulators; win[48] stays resident
// (launch_bounds(256,3) -> VGPR cap 168).
// ============================================================
__global__ __launch_bounds__(256, 3) void conv1_k(
    const float* __restrict__ x,  const float* __restrict__ w1,
    const float* __restrict__ m1, const float* __restrict__ v1, const float* __restrict__ b1,
    const float* __restrict__ w2, const float* __restrict__ m2, const float* __restrict__ v2,
    const float* __restrict__ b2,
    const float* __restrict__ w3, const float* __restrict__ m3, const float* __restrict__ v3,
    const float* __restrict__ b3,
    const float* __restrict__ w4,
    uint32_t* __restrict__ y1p,
    uint32_t* __restrict__ w2p, float* __restrict__ thr2,
    uint32_t* __restrict__ w3p, float* __restrict__ thr3,
    uint32_t* __restrict__ w4p) {

    if (blockIdx.x >= 1024) {          // ---- weight-prep blocks ----
        int j = (blockIdx.x - 1024) * 256 + threadIdx.x;
        if (j < 576) { packw_item<32, 64>(w2, w2p, j); }
        else if ((j -= 576) < 64) { thr2[j] = mk_thr(m2, v2, b2, j); }
        else if ((j -= 64) < 2304) { packw_item<64, 128>(w3, w3p, j); }
        else if ((j -= 2304) < 128) { thr3[j] = mk_thr(m3, v3, b3, j); }
        else if ((j -= 128) < 9216) { packw_item<128, 256>(w4, w4p, j); }
        return;
    }

    __shared__ float xt[34 * 104];     // 34 input rows x 102 col-floats (pad 104)
    __shared__ float th_lds[32];

    int tile = blockIdx.x;
    int tx = tile & 3;
    int ty = (tile >> 2) & 3;
    int n  = tile >> 4;
    int ph0 = ty * 16, pw0 = tx * 16;
    int r0 = 2 * ph0;
    int cf0 = pw0 * 6;                 // col-float origin (x row = 384 floats)

    for (int i = threadIdx.x; i < 34 * 102; i += 256) {
        int r = i / 102, c = i % 102;
        int gr = r0 + r, gcf = cf0 + c;
        float vv = 0.f;
        if (gr < 128 && gcf < 384)
            vv = x[(size_t)(n * 128 + gr) * 384 + gcf];
        xt[r * 104 + c] = vv;
    }
    if (threadIdx.x < 32)
        th_lds[threadIdx.x] = mk_thr(m1, v1, b1, threadIdx.x);

    int lane = threadIdx.x & 63;

    // w1 sign masks -> SGPRs via ballot (lanes 32-63 duplicate; low 32 bits valid)
    uint32_t um[27];
#pragma unroll
    for (int t = 0; t < 27; t++)
        um[t] = (uint32_t)__ballot(w1[t * 32 + (lane & 31)] < 0.f);

    __syncthreads();

    int wave = threadIdx.x >> 6;
    int px = lane & 15, py = (wave << 2) + (lane >> 4);
    int ph = ph0 + py, pw = pw0 + px;

    // 4x4x3 input window in regs (float2 LDS reads, 8B aligned)
    float win[48];
#pragma unroll
    for (int r = 0; r < 4; r++) {
        const float2* bp = (const float2*)&xt[(2 * py + r) * 104 + 6 * px];
#pragma unroll
        for (int q = 0; q < 6; q++) {
            float2 f2 = bp[q];
            win[r * 12 + 2 * q]     = f2.x;
            win[r * 12 + 2 * q + 1] = f2.y;
        }
    }

    uint32_t word = 0;
#pragma unroll
    for (int cg = 0; cg < 2; cg++) {            // 16 channels per group
        float a[16][4];
#pragma unroll
        for (int j = 0; j < 16; j++)
#pragma unroll
            for (int p = 0; p < 4; p++) a[j][p] = 0.f;
#pragma unroll
        for (int kh = 0; kh < 3; kh++)
#pragma unroll
            for (int kw = 0; kw < 3; kw++)
#pragma unroll
                for (int ci = 0; ci < 3; ci++) {
                    int tap = (kh * 3 + kw) * 3 + ci;
                    float x00 = win[kh * 12 + kw * 3 + ci];
                    float x01 = win[kh * 12 + (kw + 1) * 3 + ci];
                    float x10 = win[(kh + 1) * 12 + kw * 3 + ci];
                    float x11 = win[(kh + 1) * 12 + (kw + 1) * 3 + ci];
                    uint32_t mw = um[tap] >> (cg * 16);
#pragma unroll
                    for (int j = 0; j < 16; j++) {
                        float w = ((mw >> j) & 1u) ? -1.f : 1.f;  // uniform mask select
                        a[j][0] += x00 * w;
                        a[j][1] += x01 * w;
                        a[j][2] += x10 * w;
                        a[j][3] += x11 * w;
                    }
                }
#pragma unroll
        for (int j = 0; j < 16; j++) {
            float mx = fmaxf(fmaxf(a[j][0], a[j][1]), fmaxf(a[j][2], a[j][3]));
            int ch = cg * 16 + j;
            word |= (uint32_t)(mx < th_lds[ch]) << ch;
        }
    }

    if (ph < 63 && pw < 63)
        y1p[(n * 63 + ph) * 63 + pw] = word;
}

// ============================================================
// Layer 2: bconv(SAME, 63x63, CIN=32) + maxpool2 + bn + sign -> packed
// One wave per 4-pixel row group; lane = co. Window = 4x10 uniform words.
// ============================================================
__global__ __launch_bounds__(256) void bconv2(const uint32_t* __restrict__ y1p,
                                              const uint32_t* __restrict__ w2p,
                                              const float* __restrict__ thr2,
                                              uint2* __restrict__ y2p) {
    int gw = __builtin_amdgcn_readfirstlane(blockIdx.x * 4 + (threadIdx.x >> 6));
    int lane = threadIdx.x & 63;
    int pwg = gw & 7;          // pixel group: pw = 4*pwg + p
    int t = gw >> 3;
    int ph = t % 31;
    int n = t / 31;

    uint32_t wq[9];
#pragma unroll
    for (int tap = 0; tap < 9; tap++) wq[tap] = w2p[tap * 64 + lane];
    float th = thr2[lane];

    uint2 res[4];
    if (ph > 0 && pwg > 0) {
        int row0 = 2 * ph - 1, col0 = 8 * pwg - 1;
        uint32_t win[4][10];
#pragma unroll
        for (int r = 0; r < 4; r++)
#pragma unroll
            for (int c = 0; c < 10; c++)
                win[r][c] = y1p[(n * 63 + row0 + r) * 63 + min(col0 + c, 62)];
#pragma unroll
        for (int p = 0; p < 4; p++) {
            int a0 = 0, a1 = 0, a2 = 0, a3 = 0;
#pragma unroll
            for (int kh = 0; kh < 3; kh++)
#pragma unroll
                for (int kw = 0; kw < 3; kw++) {
                    uint32_t w = wq[kh * 3 + kw];
                    a0 += __popc(win[kh][2 * p + kw] ^ w);
                    a1 += __popc(win[kh][2 * p + kw + 1] ^ w);
                    a2 += __popc(win[kh + 1][2 * p + kw] ^ w);
                    a3 += __popc(win[kh + 1][2 * p + kw + 1] ^ w);
                }
            int best = 288 - 2 * min(min(a0, a1), min(a2, a3));
            unsigned long long bal = __ballot((float)best < th);
            res[p] = make_uint2((uint32_t)bal, (uint32_t)(bal >> 32));
        }
    } else {
#pragma unroll
        for (int p = 0; p < 4; p++) {
            int pw = 4 * pwg + p;
            int best = -1000000;
            if (pw < 31) {
#pragma unroll
                for (int dy = 0; dy < 2; dy++)
#pragma unroll
                    for (int dx = 0; dx < 2; dx++) {
                        int oh = 2 * ph + dy, ow = 2 * pw + dx;
                        int acc = 0, K = 0;
                        for (int kh = 0; kh < 3; kh++) {
                            int ih = oh - 1 + kh;
                            if (ih < 0 || ih >= 63) continue;
                            for (int kw = 0; kw < 3; kw++) {
                                int iw = ow - 1 + kw;
                                if (iw < 0 || iw >= 63) continue;
                                acc += __popc(y1p[(n * 63 + ih) * 63 + iw] ^ wq[kh * 3 + kw]);
                                K += 32;
                            }
                        }
                        best = max(best, K - 2 * acc);
                    }
            }
            unsigned long long bal = __ballot((float)best < th);
            res[p] = make_uint2((uint32_t)bal, (uint32_t)(bal >> 32));
        }
    }
    uint2 rr = res[0];
    if (lane == 1) rr = res[1];
    if (lane == 2) rr = res[2];
    if (lane == 3) rr = res[3];
    int pws = 4 * pwg + lane;
    if (lane < 4 && pws < 31)
        y2p[(n * 31 + ph) * 31 + pws] = rr;
}

// ============================================================
// Layer 3: bconv(SAME, 31x31, CIN=64) + maxpool2 + bn + sign -> packed
// Wave per (2-pixel group, co-half). Window = 4x6 uint2 uniform words.
// ============================================================
__global__ __launch_bounds__(256) void bconv3(const uint2* __restrict__ y2p,
                                              const uint32_t* __restrict__ w3p,
                                              const float* __restrict__ thr3,
                                              uint32_t* __restrict__ y3p) {
    int gw = __builtin_amdgcn_readfirstlane(blockIdx.x * 4 + (threadIdx.x >> 6));
    int lane = threadIdx.x & 63;
    int half = gw & 1;
    int t = gw >> 1;
    int pwg = t & 7;           // pw = 2*pwg + p
    t >>= 3;
    int ph = t % 15;
    int n = t / 15;
    int co = half * 64 + lane;

    uint32_t wq0[9], wq1[9];
#pragma unroll
    for (int tap = 0; tap < 9; tap++) {
        wq0[tap] = w3p[(tap * 2 + 0) * 128 + co];
        wq1[tap] = w3p[(tap * 2 + 1) * 128 + co];
    }
    float th = thr3[co];

    unsigned long long bals[2];
    if (ph > 0 && pwg > 0) {
        int row0 = 2 * ph - 1, col0 = 4 * pwg - 1;
        uint2 win[4][6];
#pragma unroll
        for (int r = 0; r < 4; r++)
#pragma unroll
            for (int c = 0; c < 6; c++)
                win[r][c] = y2p[(n * 31 + row0 + r) * 31 + min(col0 + c, 30)];
#pragma unroll
        for (int p = 0; p < 2; p++) {
            int a0 = 0, a1 = 0, a2 = 0, a3 = 0;
#pragma unroll
            for (int kh = 0; kh < 3; kh++)
#pragma unroll
                for (int kw = 0; kw < 3; kw++) {
                    int tap = kh * 3 + kw;
                    uint32_t u0 = wq0[tap], u1 = wq1[tap];
                    a0 += __popc(win[kh][2 * p + kw].x ^ u0) + __popc(win[kh][2 * p + kw].y ^ u1);
                    a1 += __popc(win[kh][2 * p + kw + 1].x ^ u0) + __popc(win[kh][2 * p + kw + 1].y ^ u1);
                    a2 += __popc(win[kh + 1][2 * p + kw].x ^ u0) + __popc(win[kh + 1][2 * p + kw].y ^ u1);
                    a3 += __popc(win[kh + 1][2 * p + kw + 1].x ^ u0) + __popc(win[kh + 1][2 * p + kw + 1].y ^ u1);
                }
            int best = 576 - 2 * min(min(a0, a1), min(a2, a3));
            bals[p] = __ballot((float)best < th);
        }
    } else {
#pragma unroll
        for (int p = 0; p < 2; p++) {
            int pw = 2 * pwg + p;
            int best = -1000000;
            if (pw < 15) {
#pragma unroll
                for (int dy = 0; dy < 2; dy++)
#pragma unroll
                    for (int dx = 0; dx < 2; dx++) {
                        int oh = 2 * ph + dy, ow = 2 * pw + dx;
                        int acc = 0, K = 0;
                        for (int kh = 0; kh < 3; kh++) {
                            int ih = oh - 1 + kh;
                            if (ih < 0 || ih >= 31) continue;
                            for (int kw = 0; kw < 3; kw++) {
                                int iw = ow - 1 + kw;
                                if (iw < 0 || iw >= 31) continue;
                                uint2 iv = y2p[(n * 31 + ih) * 31 + iw];
                                int tap = kh * 3 + kw;
                                acc += __popc(iv.x ^ wq0[tap]) + __popc(iv.y ^ wq1[tap]);
                                K += 64;
                            }
                        }
                        best = max(best, K - 2 * acc);
                    }
            }
            bals[p] = __ballot((float)best < th);
        }
    }
    uint32_t val = (uint32_t)bals[0];
    if (lane == 1) val = (uint32_t)(bals[0] >> 32);
    if (lane == 2) val = (uint32_t)bals[1];
    if (lane == 3) val = (uint32_t)(bals[1] >> 32);
    int p = lane >> 1;
    int pw = 2 * pwg + p;
    if (lane < 4 && pw < 15) {
        int pixel = (n * 15 + ph) * 15 + pw;
        y3p[pixel * 4 + half * 2 + (lane & 1)] = val;
    }
}

// ============================================================
// Layer 4: bconv(SAME, 15x15, CIN=128) + maxpool2 + bn -> f32 out
// Block per pixel; wave = one co-quad (co = wave*64 + lane).
// ============================================================
__global__ __launch_bounds__(256) void bconv4(const uint4* __restrict__ y3p,
                                              const uint32_t* __restrict__ w4p,
                                              const float* __restrict__ m,
                                              const float* __restrict__ v,
                                              const float* __restrict__ b,
                                              float* __restrict__ out) {
    int pixel = blockIdx.x;
    int lane = threadIdx.x & 63;
    int co = (threadIdx.x >> 6) * 64 + lane;
    int pw = pixel % 7;
    int t = pixel / 7;
    int ph = t % 7;
    int n = t / 7;

    uint4 wq[9];
#pragma unroll
    for (int tap = 0; tap < 9; tap++) {
        wq[tap].x = w4p[(tap * 4 + 0) * 256 + co];
        wq[tap].y = w4p[(tap * 4 + 1) * 256 + co];
        wq[tap].z = w4p[(tap * 4 + 2) * 256 + co];
        wq[tap].w = w4p[(tap * 4 + 3) * 256 + co];
    }
    int best;
    if (ph > 0 && pw > 0) {
        const uint4* p = y3p + (n * 15 + (2 * ph - 1)) * 15 + (2 * pw - 1);
        int a0 = 0, a1 = 0, a2 = 0, a3 = 0;
#pragma unroll
        for (int rr = 0; rr < 4; rr++)
#pragma unroll
            for (int cc = 0; cc < 4; cc++) {
                uint4 iv = p[rr * 15 + cc];
#pragma unroll
                for (int kh = 0; kh < 3; kh++) {
                    int dy = rr - kh;
                    if (dy < 0 || dy > 1) continue;
#pragma unroll
                    for (int kw = 0; kw < 3; kw++) {
                        int dx = cc - kw;
                        if (dx < 0 || dx > 1) continue;
                        int tap = kh * 3 + kw;
                        int pc = __popc(iv.x ^ wq[tap].x) + __popc(iv.y ^ wq[tap].y)
                               + __popc(iv.z ^ wq[tap].z) + __popc(iv.w ^ wq[tap].w);
                        if (dy == 0 && dx == 0) a0 += pc;
                        else if (dy == 0) a1 += pc;
                        else if (dx == 0) a2 += pc;
                        else a3 += pc;
                    }
                }
            }
        best = 1152 - 2 * min(min(a0, a1), min(a2, a3));
    } else {
        best = -1000000;
#pragma unroll
        for (int dy = 0; dy < 2; dy++)
#pragma unroll
            for (int dx = 0; dx < 2; dx++) {
                int oh = 2 * ph + dy, ow = 2 * pw + dx;
                int acc = 0, K = 0;
                for (int kh = 0; kh < 3; kh++) {
                    int ih = oh - 1 + kh;
                    if (ih < 0 || ih >= 15) continue;
                    for (int kw = 0; kw < 3; kw++) {
                        int iw = ow - 1 + kw;
                        if (iw < 0 || iw >= 15) continue;
                        uint4 iv = y3p[(n * 15 + ih) * 15 + iw];
                        int tap = kh * 3 + kw;
                        acc += __popc(iv.x ^ wq[tap].x) + __popc(iv.y ^ wq[tap].y)
                             + __popc(iv.z ^ wq[tap].z) + __popc(iv.w ^ wq[tap].w);
                        K += 128;
                    }
                }
                best = max(best, K - 2 * acc);
            }
    }
    float y = ((float)best - m[co]) * rsqrtf(v[co] + BN_EPS) + b[co];
    out[pixel * 256 + co] = y;
}

extern "C" void kernel_launch(void* const* d_in, const int* in_sizes, int n_in,
                              void* d_out, int out_size, void* d_ws, size_t ws_size,
                              hipStream_t stream) {
    const float* x  = (const float*)d_in[0];
    const float* w1 = (const float*)d_in[1];
    const float* m1 = (const float*)d_in[2];
    const float* v1 = (const float*)d_in[3];
    const float* b1 = (const float*)d_in[4];
    const float* w2 = (const float*)d_in[5];
    const float* m2 = (const float*)d_in[6];
    const float* v2 = (const float*)d_in[7];
    const float* b2 = (const float*)d_in[8];
    const float* w3 = (const float*)d_in[9];
    const float* m3 = (const float*)d_in[10];
    const float* v3 = (const float*)d_in[11];
    const float* b3 = (const float*)d_in[12];
    const float* w4 = (const float*)d_in[13];
    const float* m4 = (const float*)d_in[14];
    const float* v4 = (const float*)d_in[15];
    const float* b4 = (const float*)d_in[16];
    float* outp = (float*)d_out;

    char* ws = (char*)d_ws;
    size_t off = 0;
    auto take = [&](size_t bytes) -> char* {
        char* p = ws + off;
        off += (bytes + 255) & ~(size_t)255;
        return p;
    };
    uint32_t* y1p  = (uint32_t*)take((size_t)64 * 63 * 63 * 4);
    uint2*    y2p  = (uint2*)take((size_t)64 * 31 * 31 * 8);
    uint32_t* y3p  = (uint32_t*)take((size_t)64 * 15 * 15 * 16);
    uint32_t* w2p  = (uint32_t*)take(576 * 4);
    float*    thr2 = (float*)take(64 * 4);
    uint32_t* w3p  = (uint32_t*)take(2304 * 4);
    float*    thr3 = (float*)take(128 * 4);
    uint32_t* w4p  = (uint32_t*)take(9216 * 4);

    // conv1 (1024 blocks) + layer2-4 weight prep (48 blocks)
    conv1_k<<<1024 + 48, 256, 0, stream>>>(
        x, w1, m1, v1, b1, w2, m2, v2, b2, w3, m3, v3, b3, w4,
        y1p, w2p, thr2, w3p, thr3, w4p);

    bconv2<<<(64 * 31 * 8) / 4, 256, 0, stream>>>(y1p, w2p, thr2, y2p);

    bconv3<<<(64 * 15 * 8 * 2) / 4, 256, 0, stream>>>(y2p, w3p, thr3, y3p);

    bconv4<<<64 * 7 * 7, 256, 0, stream>>>((const uint4*)y3p, w4p, m4, v4, b4, outp);
}